// Round 9
// baseline (140.153 us; speedup 1.0000x reference)
//
#include <hip/hip_runtime.h>
#include <cmath>

// CapsuleLayer routing, B=64, Ni=2048, Di=16, No=32, Do=16 (fp32 in/out).
// R13: shorten the per-iter serial chain (R6-R12 falsified everything else;
// fused stuck at ~38us = 11.4K cyc/iter vs ~3K issue work).
//  (1) W never touches LDS: MFMA A-fragment lane layout (row=l&15, k-slice
//      (l>>4)*8) maps directly onto W[n][o][d][i] global layout. Each lane
//      loads 2 float4 per o and converts in-register (hi-pack for lanes<32,
//      residual lo-pack for lanes>=32). Depth-2 rolling register pipeline;
//      the last two bodies of iter nn issue (nn+1, o=0,1) so W loads stay
//      in flight across both barriers (lgkm-only barriers never drain vmcnt).
//      Removes: W ds_writes, A ds_reads, staging<->barrier coupling.
//  (2) routing reduces via DPP row_ror (VALU, ~2-4cy) instead of __shfl_xor
//      (ds_swizzle, LDS pipe ~30cy): 16-deep dependent chain collapses.
// Kept: XL x-preload (prologue-only), 2-way b-split, XCD pairing, cvt_pk,
// lgkm-only barriers (R12, proven), (512,4) bounds, gidx-major epilogue,
// R9 reduce kernel. LDS now 24.8 KB.

#define NI 2048
#define NGROUPS 256
#define NPER 8

typedef short bf16x8 __attribute__((ext_vector_type(8)));
typedef float f32x4 __attribute__((ext_vector_type(4)));

static __device__ __forceinline__ unsigned cvt_pk_bf16(float a, float b) {
  unsigned r;
  asm("v_cvt_pk_bf16_f32 %0, %1, %2" : "=v"(r) : "v"(a), "v"(b));
  return r;  // lo16 = bf16(a), hi16 = bf16(b), RNE
}
static __device__ __forceinline__ void split4_pk(float4 v, uint2& hi, uint2& lo) {
  hi.x = cvt_pk_bf16(v.x, v.y);
  hi.y = cvt_pk_bf16(v.z, v.w);
  float r0 = v.x - __uint_as_float(hi.x << 16);
  float r1 = v.y - __uint_as_float(hi.x & 0xFFFF0000u);
  float r2 = v.z - __uint_as_float(hi.y << 16);
  float r3 = v.w - __uint_as_float(hi.y & 0xFFFF0000u);
  lo.x = cvt_pk_bf16(r0, r1);
  lo.y = cvt_pk_bf16(r2, r3);
}
static __device__ __forceinline__ int swz8(int r, int u) {
  return r * 8 + ((u ^ ((r >> 2) & 1)) << 2);
}
// LDS-only barrier (R12-proven): never drains vmcnt.
static __device__ __forceinline__ void barrier_lds() {
  asm volatile("s_waitcnt lgkmcnt(0)" ::: "memory");
  __builtin_amdgcn_s_barrier();
  __builtin_amdgcn_sched_barrier(0);
}
// DPP rotate within 16-lane rows: ctrl 0x120|N = row_ror:N
template<int CTRL>
static __device__ __forceinline__ float dpp_rot(float v) {
  return __int_as_float(__builtin_amdgcn_mov_dpp(__float_as_int(v), CTRL, 0xF, 0xF, true));
}
static __device__ __forceinline__ float sum16_dpp(float v) {
  v += dpp_rot<0x128>(v); v += dpp_rot<0x124>(v);
  v += dpp_rot<0x122>(v); v += dpp_rot<0x121>(v);
  return v;
}
static __device__ __forceinline__ float max16_dpp(float v) {
  v = fmaxf(v, dpp_rot<0x128>(v)); v = fmaxf(v, dpp_rot<0x124>(v));
  v = fmaxf(v, dpp_rot<0x122>(v)); v = fmaxf(v, dpp_rot<0x121>(v));
  return v;
}
// Build MFMA A-fragment from 8 fp32 W values: hi-pack (lanes<32) / lo-pack (>=32)
static __device__ __forceinline__ bf16x8 mk_afrag(float4 v0, float4 v1, bool lo) {
  unsigned h0 = cvt_pk_bf16(v0.x, v0.y), h1 = cvt_pk_bf16(v0.z, v0.w);
  unsigned h2 = cvt_pk_bf16(v1.x, v1.y), h3 = cvt_pk_bf16(v1.z, v1.w);
  float r0 = v0.x - __uint_as_float(h0 << 16);
  float r1 = v0.y - __uint_as_float(h0 & 0xFFFF0000u);
  float r2 = v0.z - __uint_as_float(h1 << 16);
  float r3 = v0.w - __uint_as_float(h1 & 0xFFFF0000u);
  float r4 = v1.x - __uint_as_float(h2 << 16);
  float r5 = v1.y - __uint_as_float(h2 & 0xFFFF0000u);
  float r6 = v1.z - __uint_as_float(h3 << 16);
  float r7 = v1.w - __uint_as_float(h3 & 0xFFFF0000u);
  unsigned g0 = cvt_pk_bf16(r0, r1), g1 = cvt_pk_bf16(r2, r3);
  unsigned g2 = cvt_pk_bf16(r4, r5), g3 = cvt_pk_bf16(r6, r7);
  union { unsigned u[4]; bf16x8 v; } a;
  a.u[0] = lo ? g0 : h0; a.u[1] = lo ? g1 : h1;
  a.u[2] = lo ? g2 : h2; a.u[3] = lo ? g3 : h3;
  return a.v;
}

// ---------------- Fused kernel ----------------
// grid 512; xcd = bx&7, slot = bx>>3; ng = xcd*32 + (slot>>1); bh = slot&1.
// block 512 = 8 waves = (bt = wv&1: b-tile) x (oq = wv>>1: o-octet).
// A (W) direct from global to registers; B (x) from XL LDS preload.
#define XLOFF 0       // 8 n * 64 rows (s*32+b) * 8 = 4096 dwords
#define HOFF  4096    // h[b_local][o]: 32 * 33 = 1056
#define C2OFF 5152    // c2[o][b_local]: 32 * 33 = 1056
#define LDSZ  6208    // 24.8 KB
__global__ __launch_bounds__(512, 4) void caps_fused_kernel(
    const float* __restrict__ x, const float* __restrict__ W,
    float* __restrict__ partial)
{
  const int bx = blockIdx.x;
  const int xcd = bx & 7, slot = bx >> 3;
  const int ng = xcd * 32 + (slot >> 1);
  const int bh = slot & 1;
  const int t = threadIdx.x;
  const int wv = t >> 6, l = t & 63;
  const int q = l >> 4, dq = l & 15, qh = q & 1;
  const bool s_lo = (q >> 1) != 0;   // lanes >= 32 hold the lo-split k-half
  const int bt = wv & 1, oq = wv >> 1;

  __shared__ __align__(16) float lds[LDSZ];
  float* XL  = lds + XLOFF;
  float* hS  = lds + HOFF;
  float* c2S = lds + C2OFF;

  float sacc[8][4];
  #pragma unroll
  for (int oo = 0; oo < 8; ++oo)
    { sacc[oo][0] = 0.f; sacc[oo][1] = 0.f; sacc[oo][2] = 0.f; sacc[oo][3] = 0.f; }

  const int n0 = ng * NPER;
  // per-lane W address tail: [d=dq][i-base=(q&1)*8], o-slice base = oq*8
  const float* wlane = W + (size_t)dq * 16 + qh * 8 + (size_t)(oq * 8) * 256;

  // ---- prologue: preload ALL x for the group into XL (split-bf16, swizzled) ----
  #pragma unroll
  for (int m = 0; m < 2; ++m) {
    const int idx = m * 512 + t;
    const int pb = idx >> 5, pn = (idx >> 2) & 7, pi4 = idx & 3;
    float4 v = *(const float4*)(x + (size_t)(bh * 32 + pb) * (NI * 16)
                                 + (n0 + pn) * 16 + pi4 * 4);
    uint2 hi, lo;
    split4_pk(v, hi, lo);
    const int pu = pi4 >> 1, psub = (pi4 & 1) * 2;
    float* XLn = XL + pn * 512;
    *(uint2*)&XLn[swz8(pb, pu) + psub] = hi;
    *(uint2*)&XLn[swz8(32 + pb, pu) + psub] = lo;
  }
  // depth-2 W pipeline: issue (n0, o'=0,1) before the barrier (in flight across it)
  float4 wv0[2], wv1[2];
  {
    const float* p0 = wlane + (size_t)n0 * 8192;
    wv0[0] = *(const float4*)(p0);           wv1[0] = *(const float4*)(p0 + 4);
    wv0[1] = *(const float4*)(p0 + 256);     wv1[1] = *(const float4*)(p0 + 260);
  }
  barrier_lds();

  #pragma unroll 1
  for (int nn = 0; nn < NPER; ++nn) {
    // ---- phase 1: per-o: convert A from regs, refill pipeline, MFMA; h -> hS ----
    f32x4 Dv[8];
    {
      const float* XLn = XL + nn * 512;
      bf16x8 B0 = *(const bf16x8*)&XLn[swz8(bt * 16 + dq, qh)];        // x_hi
      bf16x8 B1 = *(const bf16x8*)&XLn[swz8(32 + bt * 16 + dq, qh)];   // x_lo
      #pragma unroll
      for (int oo = 0; oo < 8; ++oo) {
        bf16x8 A = mk_afrag(wv0[oo & 1], wv1[oo & 1], s_lo);
        // refill slot oo&1: (nn, oo+2) or (nn+1, oo-6)
        if (oo < 6) {
          const float* p = wlane + (size_t)(n0 + nn) * 8192 + (oo + 2) * 256;
          wv0[oo & 1] = *(const float4*)p;  wv1[oo & 1] = *(const float4*)(p + 4);
        } else if (nn < NPER - 1) {
          const float* p = wlane + (size_t)(n0 + nn + 1) * 8192 + (oo - 6) * 256;
          wv0[oo & 1] = *(const float4*)p;  wv1[oo & 1] = *(const float4*)(p + 4);
        }
        f32x4 D = {0.f, 0.f, 0.f, 0.f};
        D = __builtin_amdgcn_mfma_f32_16x16x32_bf16(A, B0, D, 0, 0, 0);
        D = __builtin_amdgcn_mfma_f32_16x16x32_bf16(A, B1, D, 0, 0, 0);
        Dv[oo] = D;
        float hs = D[0] + D[1] + D[2] + D[3];   // sum over d within q-group
        hs += __shfl_xor(hs, 16);
        hs += __shfl_xor(hs, 32);               // sum over q
        if (q == 0) hS[(bt * 16 + dq) * 33 + (oq * 8 + oo)] = hs;
      }
    }
    barrier_lds();   // syncA: hS ready

    // ---- phase 2: routing; 16-lane reduces via DPP row_ror (VALU-speed) ----
    {
      const int bl = t >> 4, op = t & 15;
      const float h0 = hS[bl * 33 + op];
      const float h1 = hS[bl * 33 + op + 16];
      const float b10 = h0 * 0.03125f, b11 = h1 * 0.03125f;
      const float mx = max16_dpp(fmaxf(b10, b11));
      const float e0 = __expf(b10 - mx), e1 = __expf(b11 - mx);
      const float S = sum16_dpp(e0 + e1);
      const float inv = 1.0f / S;
      const float b20 = b10 + e0 * inv * h0, b21 = b11 + e1 * inv * h1;
      const float mx2 = max16_dpp(fmaxf(b20, b21));
      const float e20 = __expf(b20 - mx2), e21 = __expf(b21 - mx2);
      const float S2 = sum16_dpp(e20 + e21);
      const float inv2 = 1.0f / S2;
      c2S[op * 33 + bl] = e20 * inv2;
      c2S[(op + 16) * 33 + bl] = e21 * inv2;
    }
    barrier_lds();   // syncB: c2S ready

    // ---- phase 3: weighted accumulate from retained D ----
    #pragma unroll
    for (int oo = 0; oo < 8; ++oo) {
      const float c = c2S[(oq * 8 + oo) * 33 + bt * 16 + dq];
      sacc[oo][0] += c * Dv[oo][0]; sacc[oo][1] += c * Dv[oo][1];
      sacc[oo][2] += c * Dv[oo][2]; sacc[oo][3] += c * Dv[oo][3];
    }
    // c2S reads precede next syncA; next c2S writes follow it.
  }

  // ---- epilogue: gidx-major, block-contiguous partial ----
  float* pb = partial + (size_t)ng * 32768
            + (size_t)(bh * 32 + bt * 16 + dq) * 512 + q * 4;
  #pragma unroll
  for (int oo = 0; oo < 8; ++oo) {
    *(float4*)(pb + (oq * 8 + oo) * 16)
        = make_float4(sacc[oo][0], sacc[oo][1], sacc[oo][2], sacc[oo][3]);
  }
}

// ---------------- Kernel 2: reduce 256 group-partials + squash (R9 proven) ----
__global__ __launch_bounds__(256) void caps_reduce_kernel(
    const float* __restrict__ partial, float* __restrict__ out)
{
  const int t = threadIdx.x;
  const int w4 = t >> 6, ln = t & 63;
  const int pair = blockIdx.x * 4 + w4;     // (b,o), 2048 total
  const int b = pair >> 5, o = pair & 31;
  const int d = ln & 15, cg = ln >> 4;
  const float* p = partial + (size_t)b * 512 + o * 16 + d;
  float s = 0.f;
  #pragma unroll 8
  for (int gg = cg; gg < NGROUPS; gg += 4) s += p[(size_t)gg * 32768];
  s += __shfl_xor(s, 16); s += __shfl_xor(s, 32);    // over cg
  float s2 = s * s;
  s2 += __shfl_xor(s2, 1); s2 += __shfl_xor(s2, 2);
  s2 += __shfl_xor(s2, 4); s2 += __shfl_xor(s2, 8);  // over d
  float scale = s2 / (1.0f + s2) / sqrtf(s2 + 1e-7f);
  if (ln < 16) out[(size_t)b * 512 + o * 16 + d] = scale * s;
}

extern "C" void kernel_launch(void* const* d_in, const int* in_sizes, int n_in,
                              void* d_out, int out_size, void* d_ws, size_t ws_size,
                              hipStream_t stream) {
  const float* x = (const float*)d_in[0];   // [64,2048,16]
  const float* W = (const float*)d_in[1];   // [1,2048,32,16,16]
  if (in_sizes[0] != 64 * 2048 * 16) { const float* tmp = x; x = W; W = tmp; }
  float* out = (float*)d_out;               // [64,32,16]

  float* partial = (float*)d_ws;            // 256*32768 f32 = 33.5 MB (gidx-major)

  caps_fused_kernel<<<512, 512, 0, stream>>>(x, W, partial);
  caps_reduce_kernel<<<512, 256, 0, stream>>>(partial, out);
}

// Round 11
// 119.046 us; speedup vs baseline: 1.1773x; 1.1773x over previous
//
#include <hip/hip_runtime.h>
#include <cmath>

// CapsuleLayer routing, B=64, Ni=2048, Di=16, No=32, Do=16 (fp32 in/out).
// R15 = R9 (best measured: 124.97us) + two isolated, reversible levers:
//  (1) DPP row_ror routing reduces (R13 proved correctness; never isolated):
//      the four 16-lane reduces in routing go from 16 serial ds_swizzle ops
//      (~30cy, LDS pipe) to VALU-latency row_ror chains.
//  (2) fp16 partials: fused epilogue WRITE 33.5->16.8 MB, reduce FETCH
//      33.5->16.8 MB. Precision: per-partial ~0.5 magnitude, fp16 RNE err
//      ~2e-4, CLT over 256 groups ~3e-3 on s; squash scales output err by
//      ~1/||s|| ~ 0.15 -> ~5e-4 added vs 1.18e-2 threshold.
// R14 post-mortem: cooperative merge FAILED on cross-XCD L2 non-coherence
// (partial stores invisible to other XCDs' readers; guideline 16). Reverted.
// Kept from R9 (all verified): 2-way b-split, XOR-swizzled pad-free LDS
// (conflicts 0), cvt_pk split-bf16 staging, 2-barrier single-buffer pipeline
// with prefetch 2 ahead, (512,4) bounds, XCD pairing, gidx-major epilogue.

#define NI 2048
#define NGROUPS 256
#define NPER 8

typedef short bf16x8 __attribute__((ext_vector_type(8)));
typedef float f32x4 __attribute__((ext_vector_type(4)));

static __device__ __forceinline__ unsigned cvt_pk_bf16(float a, float b) {
  unsigned r;
  asm("v_cvt_pk_bf16_f32 %0, %1, %2" : "=v"(r) : "v"(a), "v"(b));
  return r;  // lo16 = bf16(a), hi16 = bf16(b), RNE
}
// fp32 -> (hi bf16x4, lo bf16x4) with hi+lo ~ full precision
static __device__ __forceinline__ void split4_pk(float4 v, uint2& hi, uint2& lo) {
  hi.x = cvt_pk_bf16(v.x, v.y);
  hi.y = cvt_pk_bf16(v.z, v.w);
  float r0 = v.x - __uint_as_float(hi.x << 16);
  float r1 = v.y - __uint_as_float(hi.x & 0xFFFF0000u);
  float r2 = v.z - __uint_as_float(hi.y << 16);
  float r3 = v.w - __uint_as_float(hi.y & 0xFFFF0000u);
  lo.x = cvt_pk_bf16(r0, r1);
  lo.y = cvt_pk_bf16(r2, r3);
}
// dword offset of 16B unit u (0/1) of row r in a rows-of-8-dwords array,
// XOR-swizzled so stride-8 row reads spread across banks (both sides use it).
static __device__ __forceinline__ int swz8(int r, int u) {
  return r * 8 + ((u ^ ((r >> 2) & 1)) << 2);
}
// fp32 <-> fp16 scalar converts (v_cvt_f16_f32 / v_cvt_f32_f16)
static __device__ __forceinline__ unsigned short f2h(float f) {
  _Float16 h = (_Float16)f;
  union { _Float16 h; unsigned short u; } c; c.h = h; return c.u;
}
static __device__ __forceinline__ float h2f(unsigned short u) {
  union { _Float16 h; unsigned short u; } c; c.u = u; return (float)c.h;
}
// DPP rotate within 16-lane rows: ctrl 0x120|N = row_ror:N (R13-proven)
template<int CTRL>
static __device__ __forceinline__ float dpp_rot(float v) {
  return __int_as_float(__builtin_amdgcn_mov_dpp(__float_as_int(v), CTRL, 0xF, 0xF, true));
}
static __device__ __forceinline__ float sum16_dpp(float v) {
  v += dpp_rot<0x128>(v); v += dpp_rot<0x124>(v);
  v += dpp_rot<0x122>(v); v += dpp_rot<0x121>(v);
  return v;
}
static __device__ __forceinline__ float max16_dpp(float v) {
  v = fmaxf(v, dpp_rot<0x128>(v)); v = fmaxf(v, dpp_rot<0x124>(v));
  v = fmaxf(v, dpp_rot<0x122>(v)); v = fmaxf(v, dpp_rot<0x121>(v));
  return v;
}

// ---------------- Fused kernel: MFMA + in-block routing + weighted accumulate ----
// grid 512; xcd = bx&7, slot = bx>>3 (0..63); ng = xcd*32 + (slot>>1); bh = slot&1
// (both bh blocks of an ng on one XCD -> W read once per XCD from L2/L3).
// block 512 = 8 waves = (bt = wv&1: 16-b tile of the 32-b half) x (oq = wv>>1:
// o-octet). Wave: o = oq*8 .. oq*8+7, b = bt*16 .. +15.
// A = [W_hi|W_lo] (m=d, K=32 packed split), B = [x_hi],[x_lo] dup along K.
// LDS dword offsets (rows of 8 dwords, swizzled):
#define WAOFF 0        // 32 o * 32 rows (s*16+d) * 8 = 8192
#define XBOFF 8192     // 64 rows (s*32 + b_local) * 8 = 512
#define HOFF  8704     // h[b_local][o]: 32 * 33 = 1056
#define C2OFF 9760     // c2[o][b_local]: 32 * 33 = 1056
#define LDSZ  10816    // 43.3 KB
__global__ __launch_bounds__(512, 4) void caps_fused_kernel(
    const float* __restrict__ x, const float* __restrict__ W,
    unsigned short* __restrict__ partial)
{
  const int bx = blockIdx.x;
  const int xcd = bx & 7, slot = bx >> 3;
  const int ng = xcd * 32 + (slot >> 1);
  const int bh = slot & 1;
  const int t = threadIdx.x;
  const int wv = t >> 6, l = t & 63;
  const int q = l >> 4, dq = l & 15, qh = q & 1, s_a = q >> 1;
  const int bt = wv & 1, oq = wv >> 1;

  __shared__ __align__(16) float lds[LDSZ];
  float* WA  = lds + WAOFF;
  float* XB  = lds + XBOFF;
  float* hS  = lds + HOFF;
  float* c2S = lds + C2OFF;

  float sacc[8][4];
  #pragma unroll
  for (int oo = 0; oo < 8; ++oo)
    { sacc[oo][0] = 0.f; sacc[oo][1] = 0.f; sacc[oo][2] = 0.f; sacc[oo][3] = 0.f; }

  const int n0 = ng * NPER;
  // staging decompositions: W chunk c covers o = c*8 + wv; (d, i4) from t
  const int wd = (t >> 2) & 15, wi4 = t & 3;
  const int wu = wi4 >> 1, wsub = (wi4 & 1) * 2;
  const int xb = t >> 2, xi4 = t & 3;          // x staging: t < 128 (32 b)
  const int xu = xi4 >> 1, xsub = (xi4 & 1) * 2;

  // ---- prologue: load + stage n0, then prefetch n0+1 ----
  float4 wreg[4];
  float4 xreg = make_float4(0.f, 0.f, 0.f, 0.f);
  #pragma unroll
  for (int c = 0; c < 4; ++c)
    wreg[c] = *(const float4*)(W + (size_t)n0 * 8192 + c * 2048 + 4 * t);
  if (t < 128)
    xreg = *(const float4*)(x + (size_t)(bh * 32 + xb) * (NI * 16) + n0 * 16 + xi4 * 4);

  #pragma unroll
  for (int c = 0; c < 4; ++c) {
    uint2 hi, lo;
    split4_pk(wreg[c], hi, lo);
    const int rh = (c * 8 + wv) * 32 + wd;
    *(uint2*)&WA[swz8(rh, wu) + wsub] = hi;
    *(uint2*)&WA[swz8(rh + 16, wu) + wsub] = lo;
  }
  if (t < 128) {
    uint2 hi, lo;
    split4_pk(xreg, hi, lo);
    *(uint2*)&XB[swz8(xb, xu) + xsub] = hi;
    *(uint2*)&XB[swz8(32 + xb, xu) + xsub] = lo;
  }
  __syncthreads();

  {
    const size_t nb = (size_t)(n0 + 1);
    #pragma unroll
    for (int c = 0; c < 4; ++c)
      wreg[c] = *(const float4*)(W + nb * 8192 + c * 2048 + 4 * t);
    if (t < 128)
      xreg = *(const float4*)(x + (size_t)(bh * 32 + xb) * (NI * 16) + nb * 16 + xi4 * 4);
  }

  #pragma unroll 1
  for (int nn = 0; nn < NPER; ++nn) {
    // ---- phase 1: MFMA from LDS (data nn); h = row-sum(D) -> hS ----
    f32x4 Dv[8];
    {
      bf16x8 B0 = *(const bf16x8*)&XB[swz8(bt * 16 + dq, qh)];        // x_hi
      bf16x8 B1 = *(const bf16x8*)&XB[swz8(32 + bt * 16 + dq, qh)];   // x_lo
      #pragma unroll
      for (int oo = 0; oo < 8; ++oo) {
        const int o = oq * 8 + oo;
        bf16x8 A = *(const bf16x8*)&WA[swz8(o * 32 + s_a * 16 + dq, qh)];
        f32x4 D = {0.f, 0.f, 0.f, 0.f};
        D = __builtin_amdgcn_mfma_f32_16x16x32_bf16(A, B0, D, 0, 0, 0);
        D = __builtin_amdgcn_mfma_f32_16x16x32_bf16(A, B1, D, 0, 0, 0);
        Dv[oo] = D;
        float hs = D[0] + D[1] + D[2] + D[3];   // sum over d within q-group
        hs += __shfl_xor(hs, 16);
        hs += __shfl_xor(hs, 32);               // sum over q
        if (q == 0) hS[(bt * 16 + dq) * 33 + o] = hs;
      }
    }
    __syncthreads();   // syncA: hS ready; MFMA reads of WA/XB(nn) complete

    // ---- phase 2a: stage data nn+1 into WA/XB (pipelined, single buffer) ----
    if (nn < NPER - 1) {
      #pragma unroll
      for (int c = 0; c < 4; ++c) {
        uint2 hi, lo;
        split4_pk(wreg[c], hi, lo);
        const int rh = (c * 8 + wv) * 32 + wd;
        *(uint2*)&WA[swz8(rh, wu) + wsub] = hi;
        *(uint2*)&WA[swz8(rh + 16, wu) + wsub] = lo;
      }
      if (t < 128) {
        uint2 hi, lo;
        split4_pk(xreg, hi, lo);
        *(uint2*)&XB[swz8(xb, xu) + xsub] = hi;
        *(uint2*)&XB[swz8(32 + xb, xu) + xsub] = lo;
      }
    }

    // ---- phase 2b: routing; 16-lane reduces via DPP row_ror (R13-proven) ----
    {
      const int bl = t >> 4, op = t & 15;
      const float h0 = hS[bl * 33 + op];
      const float h1 = hS[bl * 33 + op + 16];
      const float b10 = h0 * 0.03125f, b11 = h1 * 0.03125f;
      const float mx = max16_dpp(fmaxf(b10, b11));
      const float e0 = __expf(b10 - mx), e1 = __expf(b11 - mx);
      const float S = sum16_dpp(e0 + e1);
      const float inv = 1.0f / S;
      const float b20 = b10 + e0 * inv * h0, b21 = b11 + e1 * inv * h1;
      const float mx2 = max16_dpp(fmaxf(b20, b21));
      const float e20 = __expf(b20 - mx2), e21 = __expf(b21 - mx2);
      const float S2 = sum16_dpp(e20 + e21);
      const float inv2 = 1.0f / S2;
      c2S[op * 33 + bl] = e20 * inv2;
      c2S[(op + 16) * 33 + bl] = e21 * inv2;
    }

    // ---- phase 2c: issue global prefetch for nn+2 ----
    if (nn < NPER - 2) {
      const size_t nb = (size_t)(n0 + nn + 2);
      #pragma unroll
      for (int c = 0; c < 4; ++c)
        wreg[c] = *(const float4*)(W + nb * 8192 + c * 2048 + 4 * t);
      if (t < 128)
        xreg = *(const float4*)(x + (size_t)(bh * 32 + xb) * (NI * 16) + nb * 16 + xi4 * 4);
    }
    __syncthreads();   // syncB: c2S ready; WA/XB(nn+1) staged

    // ---- phase 3: weighted accumulate from retained D ----
    #pragma unroll
    for (int oo = 0; oo < 8; ++oo) {
      const int o = oq * 8 + oo;
      const float c = c2S[o * 33 + bt * 16 + dq];
      sacc[oo][0] += c * Dv[oo][0]; sacc[oo][1] += c * Dv[oo][1];
      sacc[oo][2] += c * Dv[oo][2]; sacc[oo][3] += c * Dv[oo][3];
    }
    // c2S reads here precede the next syncA; next c2S writes come after it.
  }

  // ---- epilogue: gidx-major, block-contiguous, fp16 partials ----
  // partial[ng][b_global][cell], cell = o*16 + d (half elements), d = q*4 + r
  unsigned short* pb = partial + (size_t)ng * 32768
            + (size_t)(bh * 32 + bt * 16 + dq) * 512 + q * 4;
  #pragma unroll
  for (int oo = 0; oo < 8; ++oo) {
    const int o = oq * 8 + oo;
    ushort4 v;
    v.x = f2h(sacc[oo][0]); v.y = f2h(sacc[oo][1]);
    v.z = f2h(sacc[oo][2]); v.w = f2h(sacc[oo][3]);
    *(ushort4*)(pb + o * 16) = v;
  }
}

// ---------------- Kernel 2: reduce 256 fp16 group-partials + squash ----------------
__global__ __launch_bounds__(256) void caps_reduce_kernel(
    const unsigned short* __restrict__ partial, float* __restrict__ out)
{
  const int t = threadIdx.x;
  const int w4 = t >> 6, ln = t & 63;
  const int pair = blockIdx.x * 4 + w4;     // (b,o), 2048 total
  const int b = pair >> 5, o = pair & 31;
  const int d = ln & 15, cg = ln >> 4;
  const unsigned short* p = partial + (size_t)b * 512 + o * 16 + d;
  float s = 0.f;
  #pragma unroll 8
  for (int gg = cg; gg < NGROUPS; gg += 4) s += h2f(p[(size_t)gg * 32768]);
  s += __shfl_xor(s, 16); s += __shfl_xor(s, 32);    // over cg
  float s2 = s * s;
  s2 += __shfl_xor(s2, 1); s2 += __shfl_xor(s2, 2);
  s2 += __shfl_xor(s2, 4); s2 += __shfl_xor(s2, 8);  // over d
  float scale = s2 / (1.0f + s2) / sqrtf(s2 + 1e-7f);
  if (ln < 16) out[(size_t)b * 512 + o * 16 + d] = scale * s;
}

extern "C" void kernel_launch(void* const* d_in, const int* in_sizes, int n_in,
                              void* d_out, int out_size, void* d_ws, size_t ws_size,
                              hipStream_t stream) {
  const float* x = (const float*)d_in[0];   // [64,2048,16]
  const float* W = (const float*)d_in[1];   // [1,2048,32,16,16]
  if (in_sizes[0] != 64 * 2048 * 16) { const float* tmp = x; x = W; W = tmp; }
  float* out = (float*)d_out;               // [64,32,16]

  unsigned short* partial = (unsigned short*)d_ws;  // 256*32768 fp16 = 16.8 MB

  caps_fused_kernel<<<512, 512, 0, stream>>>(x, W, partial);
  caps_reduce_kernel<<<512, 256, 0, stream>>>(partial, out);
}

// Round 12
// 116.864 us; speedup vs baseline: 1.1993x; 1.0187x over previous
//
#include <hip/hip_runtime.h>
#include <cmath>

// CapsuleLayer routing, B=64, Ni=2048, Di=16, No=32, Do=16 (fp32 in/out).
// R16 = R15 (best: 119.05us) + hS4 restructure: remove the 16 serial
// ds_swizzle ops (__shfl_xor q-reduce) and the divergent q==0 write from
// INSIDE the MFMA critical loop. Each lane now writes its q-partial
// rowsum to hS4[b][o][q] (stride-132 rows -> write banks (dq*4+q)%32,
// 2-way = free); routing reads the 4 partials as one ds_read_b128 per
// o-half and sums in-register. P1 = pure MFMA + 3 adds + 1 ds_write/oo.
// Kept from R15 (all verified): fp16 partials (reduce FETCH halved),
// DPP row_ror routing reduces, 2-way b-split, XOR-swizzled pad-free LDS,
// cvt_pk split-bf16 staging, 2-barrier single-buffer pipeline with
// prefetch 2 ahead, (512,4) bounds, XCD pairing, gidx-major epilogue.

#define NI 2048
#define NGROUPS 256
#define NPER 8

typedef short bf16x8 __attribute__((ext_vector_type(8)));
typedef float f32x4 __attribute__((ext_vector_type(4)));

static __device__ __forceinline__ unsigned cvt_pk_bf16(float a, float b) {
  unsigned r;
  asm("v_cvt_pk_bf16_f32 %0, %1, %2" : "=v"(r) : "v"(a), "v"(b));
  return r;  // lo16 = bf16(a), hi16 = bf16(b), RNE
}
// fp32 -> (hi bf16x4, lo bf16x4) with hi+lo ~ full precision
static __device__ __forceinline__ void split4_pk(float4 v, uint2& hi, uint2& lo) {
  hi.x = cvt_pk_bf16(v.x, v.y);
  hi.y = cvt_pk_bf16(v.z, v.w);
  float r0 = v.x - __uint_as_float(hi.x << 16);
  float r1 = v.y - __uint_as_float(hi.x & 0xFFFF0000u);
  float r2 = v.z - __uint_as_float(hi.y << 16);
  float r3 = v.w - __uint_as_float(hi.y & 0xFFFF0000u);
  lo.x = cvt_pk_bf16(r0, r1);
  lo.y = cvt_pk_bf16(r2, r3);
}
// dword offset of 16B unit u (0/1) of row r in a rows-of-8-dwords array,
// XOR-swizzled so stride-8 row reads spread across banks (both sides use it).
static __device__ __forceinline__ int swz8(int r, int u) {
  return r * 8 + ((u ^ ((r >> 2) & 1)) << 2);
}
// fp32 <-> fp16 scalar converts
static __device__ __forceinline__ unsigned short f2h(float f) {
  _Float16 h = (_Float16)f;
  union { _Float16 h; unsigned short u; } c; c.h = h; return c.u;
}
static __device__ __forceinline__ float h2f(unsigned short u) {
  union { _Float16 h; unsigned short u; } c; c.u = u; return (float)c.h;
}
// DPP rotate within 16-lane rows: ctrl 0x120|N = row_ror:N (R13/R15-proven)
template<int CTRL>
static __device__ __forceinline__ float dpp_rot(float v) {
  return __int_as_float(__builtin_amdgcn_mov_dpp(__float_as_int(v), CTRL, 0xF, 0xF, true));
}
static __device__ __forceinline__ float sum16_dpp(float v) {
  v += dpp_rot<0x128>(v); v += dpp_rot<0x124>(v);
  v += dpp_rot<0x122>(v); v += dpp_rot<0x121>(v);
  return v;
}
static __device__ __forceinline__ float max16_dpp(float v) {
  v = fmaxf(v, dpp_rot<0x128>(v)); v = fmaxf(v, dpp_rot<0x124>(v));
  v = fmaxf(v, dpp_rot<0x122>(v)); v = fmaxf(v, dpp_rot<0x121>(v));
  return v;
}

// ---------------- Fused kernel: MFMA + in-block routing + weighted accumulate ----
// grid 512; xcd = bx&7, slot = bx>>3 (0..63); ng = xcd*32 + (slot>>1); bh = slot&1
// block 512 = 8 waves = (bt = wv&1: 16-b tile) x (oq = wv>>1: o-octet).
// A = [W_hi|W_lo] (m=d, K=32 packed split), B = [x_hi],[x_lo] dup along K.
// LDS dword offsets:
#define WAOFF 0        // 32 o * 32 rows (s*16+d) * 8 = 8192 (swizzled)
#define XBOFF 8192     // 64 rows (s*32 + b_local) * 8 = 512 (swizzled)
#define H4OFF 8704     // hS4[b][o][q]: 32 rows * 132 (32*4 + 4 pad) = 4224
#define C2OFF 12928    // c2[o][b_local]: 32 * 33 = 1056
#define LDSZ  13984    // 55.9 KB -> 2 blocks/CU
__global__ __launch_bounds__(512, 4) void caps_fused_kernel(
    const float* __restrict__ x, const float* __restrict__ W,
    unsigned short* __restrict__ partial)
{
  const int bx = blockIdx.x;
  const int xcd = bx & 7, slot = bx >> 3;
  const int ng = xcd * 32 + (slot >> 1);
  const int bh = slot & 1;
  const int t = threadIdx.x;
  const int wv = t >> 6, l = t & 63;
  const int q = l >> 4, dq = l & 15, qh = q & 1, s_a = q >> 1;
  const int bt = wv & 1, oq = wv >> 1;

  __shared__ __align__(16) float lds[LDSZ];
  float* WA  = lds + WAOFF;
  float* XB  = lds + XBOFF;
  float* hS4 = lds + H4OFF;
  float* c2S = lds + C2OFF;

  float sacc[8][4];
  #pragma unroll
  for (int oo = 0; oo < 8; ++oo)
    { sacc[oo][0] = 0.f; sacc[oo][1] = 0.f; sacc[oo][2] = 0.f; sacc[oo][3] = 0.f; }

  const int n0 = ng * NPER;
  // staging decompositions: W chunk c covers o = c*8 + wv; (d, i4) from t
  const int wd = (t >> 2) & 15, wi4 = t & 3;
  const int wu = wi4 >> 1, wsub = (wi4 & 1) * 2;
  const int xb = t >> 2, xi4 = t & 3;          // x staging: t < 128 (32 b)
  const int xu = xi4 >> 1, xsub = (xi4 & 1) * 2;
  // hS4 write base for this lane: row b = bt*16+dq, column block q
  const int h4w = (bt * 16 + dq) * 132 + q;

  // ---- prologue: load + stage n0, then prefetch n0+1 ----
  float4 wreg[4];
  float4 xreg = make_float4(0.f, 0.f, 0.f, 0.f);
  #pragma unroll
  for (int c = 0; c < 4; ++c)
    wreg[c] = *(const float4*)(W + (size_t)n0 * 8192 + c * 2048 + 4 * t);
  if (t < 128)
    xreg = *(const float4*)(x + (size_t)(bh * 32 + xb) * (NI * 16) + n0 * 16 + xi4 * 4);

  #pragma unroll
  for (int c = 0; c < 4; ++c) {
    uint2 hi, lo;
    split4_pk(wreg[c], hi, lo);
    const int rh = (c * 8 + wv) * 32 + wd;
    *(uint2*)&WA[swz8(rh, wu) + wsub] = hi;
    *(uint2*)&WA[swz8(rh + 16, wu) + wsub] = lo;
  }
  if (t < 128) {
    uint2 hi, lo;
    split4_pk(xreg, hi, lo);
    *(uint2*)&XB[swz8(xb, xu) + xsub] = hi;
    *(uint2*)&XB[swz8(32 + xb, xu) + xsub] = lo;
  }
  __syncthreads();

  {
    const size_t nb = (size_t)(n0 + 1);
    #pragma unroll
    for (int c = 0; c < 4; ++c)
      wreg[c] = *(const float4*)(W + nb * 8192 + c * 2048 + 4 * t);
    if (t < 128)
      xreg = *(const float4*)(x + (size_t)(bh * 32 + xb) * (NI * 16) + nb * 16 + xi4 * 4);
  }

  #pragma unroll 1
  for (int nn = 0; nn < NPER; ++nn) {
    // ---- phase 1: MFMA from LDS (data nn); q-partial rowsums -> hS4 ----
    // (no shuffles, no divergent write: all 64 lanes ds_write_b32, banks
    //  (dq*4+q)%32 = 2-way aliased = free)
    f32x4 Dv[8];
    {
      bf16x8 B0 = *(const bf16x8*)&XB[swz8(bt * 16 + dq, qh)];        // x_hi
      bf16x8 B1 = *(const bf16x8*)&XB[swz8(32 + bt * 16 + dq, qh)];   // x_lo
      #pragma unroll
      for (int oo = 0; oo < 8; ++oo) {
        const int o = oq * 8 + oo;
        bf16x8 A = *(const bf16x8*)&WA[swz8(o * 32 + s_a * 16 + dq, qh)];
        f32x4 D = {0.f, 0.f, 0.f, 0.f};
        D = __builtin_amdgcn_mfma_f32_16x16x32_bf16(A, B0, D, 0, 0, 0);
        D = __builtin_amdgcn_mfma_f32_16x16x32_bf16(A, B1, D, 0, 0, 0);
        Dv[oo] = D;
        hS4[h4w + o * 4] = D[0] + D[1] + D[2] + D[3];  // q-partial of h[b][o]
      }
    }
    __syncthreads();   // syncA: hS4 ready; MFMA reads of WA/XB(nn) complete

    // ---- phase 2a: stage data nn+1 into WA/XB (pipelined, single buffer) ----
    if (nn < NPER - 1) {
      #pragma unroll
      for (int c = 0; c < 4; ++c) {
        uint2 hi, lo;
        split4_pk(wreg[c], hi, lo);
        const int rh = (c * 8 + wv) * 32 + wd;
        *(uint2*)&WA[swz8(rh, wu) + wsub] = hi;
        *(uint2*)&WA[swz8(rh + 16, wu) + wsub] = lo;
      }
      if (t < 128) {
        uint2 hi, lo;
        split4_pk(xreg, hi, lo);
        *(uint2*)&XB[swz8(xb, xu) + xsub] = hi;
        *(uint2*)&XB[swz8(32 + xb, xu) + xsub] = lo;
      }
    }

    // ---- phase 2b: routing; h = sum of 4 q-partials (b128 reads);
    //      16-lane reduces via DPP row_ror (R15-proven) ----
    {
      const int bl = t >> 4, op = t & 15;
      f32x4 ha = *(const f32x4*)&hS4[bl * 132 + op * 4];
      f32x4 hb = *(const f32x4*)&hS4[bl * 132 + (op + 16) * 4];
      const float h0 = (ha[0] + ha[1]) + (ha[2] + ha[3]);
      const float h1 = (hb[0] + hb[1]) + (hb[2] + hb[3]);
      const float b10 = h0 * 0.03125f, b11 = h1 * 0.03125f;
      const float mx = max16_dpp(fmaxf(b10, b11));
      const float e0 = __expf(b10 - mx), e1 = __expf(b11 - mx);
      const float S = sum16_dpp(e0 + e1);
      const float inv = 1.0f / S;
      const float b20 = b10 + e0 * inv * h0, b21 = b11 + e1 * inv * h1;
      const float mx2 = max16_dpp(fmaxf(b20, b21));
      const float e20 = __expf(b20 - mx2), e21 = __expf(b21 - mx2);
      const float S2 = sum16_dpp(e20 + e21);
      const float inv2 = 1.0f / S2;
      c2S[op * 33 + bl] = e20 * inv2;
      c2S[(op + 16) * 33 + bl] = e21 * inv2;
    }

    // ---- phase 2c: issue global prefetch for nn+2 ----
    if (nn < NPER - 2) {
      const size_t nb = (size_t)(n0 + nn + 2);
      #pragma unroll
      for (int c = 0; c < 4; ++c)
        wreg[c] = *(const float4*)(W + nb * 8192 + c * 2048 + 4 * t);
      if (t < 128)
        xreg = *(const float4*)(x + (size_t)(bh * 32 + xb) * (NI * 16) + nb * 16 + xi4 * 4);
    }
    __syncthreads();   // syncB: c2S ready; WA/XB(nn+1) staged

    // ---- phase 3: weighted accumulate from retained D ----
    #pragma unroll
    for (int oo = 0; oo < 8; ++oo) {
      const int o = oq * 8 + oo;
      const float c = c2S[o * 33 + bt * 16 + dq];
      sacc[oo][0] += c * Dv[oo][0]; sacc[oo][1] += c * Dv[oo][1];
      sacc[oo][2] += c * Dv[oo][2]; sacc[oo][3] += c * Dv[oo][3];
    }
    // c2S reads here precede the next syncA; next c2S writes come after it.
    // hS4(nn+1) writes come after syncB -> don't race phase-2b reads of (nn).
  }

  // ---- epilogue: gidx-major, block-contiguous, fp16 partials ----
  // partial[ng][b_global][cell], cell = o*16 + d (half elements), d = q*4 + r
  unsigned short* pb = partial + (size_t)ng * 32768
            + (size_t)(bh * 32 + bt * 16 + dq) * 512 + q * 4;
  #pragma unroll
  for (int oo = 0; oo < 8; ++oo) {
    const int o = oq * 8 + oo;
    ushort4 v;
    v.x = f2h(sacc[oo][0]); v.y = f2h(sacc[oo][1]);
    v.z = f2h(sacc[oo][2]); v.w = f2h(sacc[oo][3]);
    *(ushort4*)(pb + o * 16) = v;
  }
}

// ---------------- Kernel 2: reduce 256 fp16 group-partials + squash ----------------
__global__ __launch_bounds__(256) void caps_reduce_kernel(
    const unsigned short* __restrict__ partial, float* __restrict__ out)
{
  const int t = threadIdx.x;
  const int w4 = t >> 6, ln = t & 63;
  const int pair = blockIdx.x * 4 + w4;     // (b,o), 2048 total
  const int b = pair >> 5, o = pair & 31;
  const int d = ln & 15, cg = ln >> 4;
  const unsigned short* p = partial + (size_t)b * 512 + o * 16 + d;
  float s = 0.f;
  #pragma unroll 8
  for (int gg = cg; gg < NGROUPS; gg += 4) s += h2f(p[(size_t)gg * 32768]);
  s += __shfl_xor(s, 16); s += __shfl_xor(s, 32);    // over cg
  float s2 = s * s;
  s2 += __shfl_xor(s2, 1); s2 += __shfl_xor(s2, 2);
  s2 += __shfl_xor(s2, 4); s2 += __shfl_xor(s2, 8);  // over d
  float scale = s2 / (1.0f + s2) / sqrtf(s2 + 1e-7f);
  if (ln < 16) out[(size_t)b * 512 + o * 16 + d] = scale * s;
}

extern "C" void kernel_launch(void* const* d_in, const int* in_sizes, int n_in,
                              void* d_out, int out_size, void* d_ws, size_t ws_size,
                              hipStream_t stream) {
  const float* x = (const float*)d_in[0];   // [64,2048,16]
  const float* W = (const float*)d_in[1];   // [1,2048,32,16,16]
  if (in_sizes[0] != 64 * 2048 * 16) { const float* tmp = x; x = W; W = tmp; }
  float* out = (float*)d_out;               // [64,32,16]

  unsigned short* partial = (unsigned short*)d_ws;  // 256*32768 fp16 = 16.8 MB

  caps_fused_kernel<<<512, 512, 0, stream>>>(x, W, partial);
  caps_reduce_kernel<<<512, 256, 0, stream>>>(partial, out);
}

// Round 13
// 114.794 us; speedup vs baseline: 1.2209x; 1.0180x over previous
//
#include <hip/hip_runtime.h>
#include <cmath>

// CapsuleLayer routing, B=64, Ni=2048, Di=16, No=32, Do=16 (fp32 in/out).
// R17 = R16 (best: 116.86us) + bf16-ONLY W (drop the W lo-split):
//   K=32 packs A=[Whi|Whi] vs B=[x_hi; x_lo] -> D = Whi*(x_hi+x_lo) in ONE
//   MFMA per oo (was 2), one B-frag read (was 2), WA 32->16 KB (same proven
//   2-way-free bank pattern), W conversion 48->8 VALU/thread/iter.
//   Error budget: W ~U[-0.43,0.43], bf16 err ~2.5e-4 rms -> hat ~1e-3 ->
//   s ~2e-3 (sum c2^2 ~ 2) -> x0.16 squash scale -> ~2e-3 added; total ~4e-3
//   vs threshold 1.18e-2. x keeps full hi+lo split (feeds routing too).
// Kept from R16 (all verified): hS4 q-partial rowsums (no shuffles in MFMA
// loop), fp16 partials, DPP row_ror routing reduces, 2-way b-split,
// XOR-swizzled pad-free LDS (conflicts 0), cvt_pk staging, 2-barrier
// single-buffer pipeline with prefetch 2 ahead, (512,4) bounds, XCD pairing,
// gidx-major epilogue, R9 reduce kernel.

#define NI 2048
#define NGROUPS 256
#define NPER 8

typedef short bf16x8 __attribute__((ext_vector_type(8)));
typedef float f32x4 __attribute__((ext_vector_type(4)));

static __device__ __forceinline__ unsigned cvt_pk_bf16(float a, float b) {
  unsigned r;
  asm("v_cvt_pk_bf16_f32 %0, %1, %2" : "=v"(r) : "v"(a), "v"(b));
  return r;  // lo16 = bf16(a), hi16 = bf16(b), RNE
}
// fp32 -> (hi bf16x4, lo bf16x4) with hi+lo ~ full precision (x staging)
static __device__ __forceinline__ void split4_pk(float4 v, uint2& hi, uint2& lo) {
  hi.x = cvt_pk_bf16(v.x, v.y);
  hi.y = cvt_pk_bf16(v.z, v.w);
  float r0 = v.x - __uint_as_float(hi.x << 16);
  float r1 = v.y - __uint_as_float(hi.x & 0xFFFF0000u);
  float r2 = v.z - __uint_as_float(hi.y << 16);
  float r3 = v.w - __uint_as_float(hi.y & 0xFFFF0000u);
  lo.x = cvt_pk_bf16(r0, r1);
  lo.y = cvt_pk_bf16(r2, r3);
}
// fp32x4 -> bf16x4 (hi only, W staging)
static __device__ __forceinline__ uint2 pack4_bf16(float4 v) {
  uint2 hi;
  hi.x = cvt_pk_bf16(v.x, v.y);
  hi.y = cvt_pk_bf16(v.z, v.w);
  return hi;
}
// dword offset of 16B unit u (0/1) of row r in a rows-of-8-dwords array,
// XOR-swizzled so stride-8 row reads spread across banks (both sides use it).
static __device__ __forceinline__ int swz8(int r, int u) {
  return r * 8 + ((u ^ ((r >> 2) & 1)) << 2);
}
// fp32 <-> fp16 scalar converts
static __device__ __forceinline__ unsigned short f2h(float f) {
  _Float16 h = (_Float16)f;
  union { _Float16 h; unsigned short u; } c; c.h = h; return c.u;
}
static __device__ __forceinline__ float h2f(unsigned short u) {
  union { _Float16 h; unsigned short u; } c; c.u = u; return (float)c.h;
}
// DPP rotate within 16-lane rows: ctrl 0x120|N = row_ror:N (R13/R15-proven)
template<int CTRL>
static __device__ __forceinline__ float dpp_rot(float v) {
  return __int_as_float(__builtin_amdgcn_mov_dpp(__float_as_int(v), CTRL, 0xF, 0xF, true));
}
static __device__ __forceinline__ float sum16_dpp(float v) {
  v += dpp_rot<0x128>(v); v += dpp_rot<0x124>(v);
  v += dpp_rot<0x122>(v); v += dpp_rot<0x121>(v);
  return v;
}
static __device__ __forceinline__ float max16_dpp(float v) {
  v = fmaxf(v, dpp_rot<0x128>(v)); v = fmaxf(v, dpp_rot<0x124>(v));
  v = fmaxf(v, dpp_rot<0x122>(v)); v = fmaxf(v, dpp_rot<0x121>(v));
  return v;
}

// ---------------- Fused kernel: MFMA + in-block routing + weighted accumulate ----
// grid 512; xcd = bx&7, slot = bx>>3 (0..63); ng = xcd*32 + (slot>>1); bh = slot&1
// block 512 = 8 waves = (bt = wv&1: 16-b tile) x (oq = wv>>1: o-octet).
// A = [Whi|Whi] (m=d, K=32 dup), B = [x_hi; x_lo] stacked along K.
// LDS dword offsets:
#define WAOFF 0        // 32 o * 16 rows (d) * 8 = 4096 (swizzled, bf16 hi only)
#define XBOFF 4096     // 64 rows (s*32 + b_local) * 8 = 512 (swizzled)
#define H4OFF 4608     // hS4[b][o][q]: 32 rows * 132 (32*4 + 4 pad) = 4224
#define C2OFF 8832     // c2[o][b_local]: 32 * 33 = 1056
#define LDSZ  9888     // 39.6 KB -> 2 blocks/CU
__global__ __launch_bounds__(512, 4) void caps_fused_kernel(
    const float* __restrict__ x, const float* __restrict__ W,
    unsigned short* __restrict__ partial)
{
  const int bx = blockIdx.x;
  const int xcd = bx & 7, slot = bx >> 3;
  const int ng = xcd * 32 + (slot >> 1);
  const int bh = slot & 1;
  const int t = threadIdx.x;
  const int wv = t >> 6, l = t & 63;
  const int q = l >> 4, dq = l & 15, qh = q & 1, sx = q >> 1;
  const int bt = wv & 1, oq = wv >> 1;

  __shared__ __align__(16) float lds[LDSZ];
  float* WA  = lds + WAOFF;
  float* XB  = lds + XBOFF;
  float* hS4 = lds + H4OFF;
  float* c2S = lds + C2OFF;

  float sacc[8][4];
  #pragma unroll
  for (int oo = 0; oo < 8; ++oo)
    { sacc[oo][0] = 0.f; sacc[oo][1] = 0.f; sacc[oo][2] = 0.f; sacc[oo][3] = 0.f; }

  const int n0 = ng * NPER;
  // staging decompositions: W chunk c covers o = c*8 + wv; (d, i4) from t
  const int wd = (t >> 2) & 15, wi4 = t & 3;
  const int wu = wi4 >> 1, wsub = (wi4 & 1) * 2;
  const int xb = t >> 2, xi4 = t & 3;          // x staging: t < 128 (32 b)
  const int xu = xi4 >> 1, xsub = (xi4 & 1) * 2;
  // hS4 write base for this lane: row b = bt*16+dq, column block q
  const int h4w = (bt * 16 + dq) * 132 + q;

  // ---- prologue: load + stage n0, then prefetch n0+1 ----
  float4 wreg[4];
  float4 xreg = make_float4(0.f, 0.f, 0.f, 0.f);
  #pragma unroll
  for (int c = 0; c < 4; ++c)
    wreg[c] = *(const float4*)(W + (size_t)n0 * 8192 + c * 2048 + 4 * t);
  if (t < 128)
    xreg = *(const float4*)(x + (size_t)(bh * 32 + xb) * (NI * 16) + n0 * 16 + xi4 * 4);

  #pragma unroll
  for (int c = 0; c < 4; ++c)
    *(uint2*)&WA[swz8((c * 8 + wv) * 16 + wd, wu) + wsub] = pack4_bf16(wreg[c]);
  if (t < 128) {
    uint2 hi, lo;
    split4_pk(xreg, hi, lo);
    *(uint2*)&XB[swz8(xb, xu) + xsub] = hi;
    *(uint2*)&XB[swz8(32 + xb, xu) + xsub] = lo;
  }
  __syncthreads();

  {
    const size_t nb = (size_t)(n0 + 1);
    #pragma unroll
    for (int c = 0; c < 4; ++c)
      wreg[c] = *(const float4*)(W + nb * 8192 + c * 2048 + 4 * t);
    if (t < 128)
      xreg = *(const float4*)(x + (size_t)(bh * 32 + xb) * (NI * 16) + nb * 16 + xi4 * 4);
  }

  #pragma unroll 1
  for (int nn = 0; nn < NPER; ++nn) {
    // ---- phase 1: one MFMA per oo; q-partial rowsums -> hS4 ----
    f32x4 Dv[8];
    {
      // B frag: K-slice q*8..+7 -> rows (q>>1)*32 + b (x_hi for q<2, x_lo else)
      bf16x8 B = *(const bf16x8*)&XB[swz8(sx * 32 + bt * 16 + dq, qh)];
      #pragma unroll
      for (int oo = 0; oo < 8; ++oo) {
        const int o = oq * 8 + oo;
        // A frag: Whi row (o*16+d), i-slice qh*8 (dup along K for q>=2)
        bf16x8 A = *(const bf16x8*)&WA[swz8(o * 16 + dq, qh)];
        f32x4 D = {0.f, 0.f, 0.f, 0.f};
        D = __builtin_amdgcn_mfma_f32_16x16x32_bf16(A, B, D, 0, 0, 0);
        Dv[oo] = D;
        hS4[h4w + o * 4] = D[0] + D[1] + D[2] + D[3];  // q-partial of h[b][o]
      }
    }
    __syncthreads();   // syncA: hS4 ready; MFMA reads of WA/XB(nn) complete

    // ---- phase 2a: stage data nn+1 into WA/XB (pipelined, single buffer) ----
    if (nn < NPER - 1) {
      #pragma unroll
      for (int c = 0; c < 4; ++c)
        *(uint2*)&WA[swz8((c * 8 + wv) * 16 + wd, wu) + wsub] = pack4_bf16(wreg[c]);
      if (t < 128) {
        uint2 hi, lo;
        split4_pk(xreg, hi, lo);
        *(uint2*)&XB[swz8(xb, xu) + xsub] = hi;
        *(uint2*)&XB[swz8(32 + xb, xu) + xsub] = lo;
      }
    }

    // ---- phase 2b: routing; h = sum of 4 q-partials (b128 reads);
    //      16-lane reduces via DPP row_ror (R15-proven) ----
    {
      const int bl = t >> 4, op = t & 15;
      f32x4 ha = *(const f32x4*)&hS4[bl * 132 + op * 4];
      f32x4 hb = *(const f32x4*)&hS4[bl * 132 + (op + 16) * 4];
      const float h0 = (ha[0] + ha[1]) + (ha[2] + ha[3]);
      const float h1 = (hb[0] + hb[1]) + (hb[2] + hb[3]);
      const float b10 = h0 * 0.03125f, b11 = h1 * 0.03125f;
      const float mx = max16_dpp(fmaxf(b10, b11));
      const float e0 = __expf(b10 - mx), e1 = __expf(b11 - mx);
      const float S = sum16_dpp(e0 + e1);
      const float inv = 1.0f / S;
      const float b20 = b10 + e0 * inv * h0, b21 = b11 + e1 * inv * h1;
      const float mx2 = max16_dpp(fmaxf(b20, b21));
      const float e20 = __expf(b20 - mx2), e21 = __expf(b21 - mx2);
      const float S2 = sum16_dpp(e20 + e21);
      const float inv2 = 1.0f / S2;
      c2S[op * 33 + bl] = e20 * inv2;
      c2S[(op + 16) * 33 + bl] = e21 * inv2;
    }

    // ---- phase 2c: issue global prefetch for nn+2 ----
    if (nn < NPER - 2) {
      const size_t nb = (size_t)(n0 + nn + 2);
      #pragma unroll
      for (int c = 0; c < 4; ++c)
        wreg[c] = *(const float4*)(W + nb * 8192 + c * 2048 + 4 * t);
      if (t < 128)
        xreg = *(const float4*)(x + (size_t)(bh * 32 + xb) * (NI * 16) + nb * 16 + xi4 * 4);
    }
    __syncthreads();   // syncB: c2S ready; WA/XB(nn+1) staged

    // ---- phase 3: weighted accumulate from retained D ----
    #pragma unroll
    for (int oo = 0; oo < 8; ++oo) {
      const int o = oq * 8 + oo;
      const float c = c2S[o * 33 + bt * 16 + dq];
      sacc[oo][0] += c * Dv[oo][0]; sacc[oo][1] += c * Dv[oo][1];
      sacc[oo][2] += c * Dv[oo][2]; sacc[oo][3] += c * Dv[oo][3];
    }
    // c2S reads here precede the next syncA; next c2S writes come after it.
    // hS4(nn+1) writes come after syncB -> don't race phase-2b reads of (nn).
  }

  // ---- epilogue: gidx-major, block-contiguous, fp16 partials ----
  // partial[ng][b_global][cell], cell = o*16 + d (half elements), d = q*4 + r
  unsigned short* pb = partial + (size_t)ng * 32768
            + (size_t)(bh * 32 + bt * 16 + dq) * 512 + q * 4;
  #pragma unroll
  for (int oo = 0; oo < 8; ++oo) {
    const int o = oq * 8 + oo;
    ushort4 v;
    v.x = f2h(sacc[oo][0]); v.y = f2h(sacc[oo][1]);
    v.z = f2h(sacc[oo][2]); v.w = f2h(sacc[oo][3]);
    *(ushort4*)(pb + o * 16) = v;
  }
}

// ---------------- Kernel 2: reduce 256 fp16 group-partials + squash ----------------
__global__ __launch_bounds__(256) void caps_reduce_kernel(
    const unsigned short* __restrict__ partial, float* __restrict__ out)
{
  const int t = threadIdx.x;
  const int w4 = t >> 6, ln = t & 63;
  const int pair = blockIdx.x * 4 + w4;     // (b,o), 2048 total
  const int b = pair >> 5, o = pair & 31;
  const int d = ln & 15, cg = ln >> 4;
  const unsigned short* p = partial + (size_t)b * 512 + o * 16 + d;
  float s = 0.f;
  #pragma unroll 8
  for (int gg = cg; gg < NGROUPS; gg += 4) s += h2f(p[(size_t)gg * 32768]);
  s += __shfl_xor(s, 16); s += __shfl_xor(s, 32);    // over cg
  float s2 = s * s;
  s2 += __shfl_xor(s2, 1); s2 += __shfl_xor(s2, 2);
  s2 += __shfl_xor(s2, 4); s2 += __shfl_xor(s2, 8);  // over d
  float scale = s2 / (1.0f + s2) / sqrtf(s2 + 1e-7f);
  if (ln < 16) out[(size_t)b * 512 + o * 16 + d] = scale * s;
}

extern "C" void kernel_launch(void* const* d_in, const int* in_sizes, int n_in,
                              void* d_out, int out_size, void* d_ws, size_t ws_size,
                              hipStream_t stream) {
  const float* x = (const float*)d_in[0];   // [64,2048,16]
  const float* W = (const float*)d_in[1];   // [1,2048,32,16,16]
  if (in_sizes[0] != 64 * 2048 * 16) { const float* tmp = x; x = W; W = tmp; }
  float* out = (float*)d_out;               // [64,32,16]

  unsigned short* partial = (unsigned short*)d_ws;  // 256*32768 fp16 = 16.8 MB

  caps_fused_kernel<<<512, 512, 0, stream>>>(x, W, partial);
  caps_reduce_kernel<<<512, 256, 0, stream>>>(partial, out);
}